// Round 10
// baseline (616.731 us; speedup 1.0000x reference)
//
#include <hip/hip_runtime.h>
#include <hip/hip_bf16.h>
#include <stdint.h>

// Problem constants
#define NB 2
#define NT 4096
#define NC 768
#define NHEAD 12
#define HS 64
#define MTOK (NB * NT)      // 8192
#define C3 (3 * NC)         // 2304

typedef __bf16 bf16x8 __attribute__((ext_vector_type(8)));
typedef float f32x4 __attribute__((ext_vector_type(4)));

#define KSCALE_LOG2E 0.18033688011f   // (1/sqrt(64)) * log2(e)

__device__ __forceinline__ unsigned short f2bf(float f) {  // RNE
  union { float f; uint32_t u; } v; v.f = f;
  uint32_t r = v.u + 0x7fffu + ((v.u >> 16) & 1u);
  return (unsigned short)(r >> 16);
}
__device__ __forceinline__ unsigned short bft(float f) {   // truncate
  return (unsigned short)(__builtin_bit_cast(unsigned int, f) >> 16);
}

// async global->LDS, 16B per lane: lane i lands at ldsbase + i*16B.
__device__ __forceinline__ void gload_lds16(const unsigned short* g, unsigned short* ldsbase) {
  __builtin_amdgcn_global_load_lds(
      (const __attribute__((address_space(1))) unsigned int*)g,
      (__attribute__((address_space(3))) unsigned int*)ldsbase, 16, 0, 0);
}

__device__ __forceinline__ f32x4 mfma16(bf16x8 a, bf16x8 b, f32x4 c) {
  return __builtin_amdgcn_mfma_f32_16x16x32_bf16(a, b, c, 0, 0, 0);
}

// ---------------- prep: coalesced LDS-tiled transposes + x cast ----------------
__global__ __launch_bounds__(256) void prep(
    const float* __restrict__ x, const float* __restrict__ wa, const float* __restrict__ wp,
    unsigned short* __restrict__ xb, unsigned short* __restrict__ waT,
    unsigned short* __restrict__ wpT) {
  const int bx = blockIdx.x;
  if (bx < 576) {
    __shared__ float tile[64][65];
    const float* src; unsigned short* dst;
    int srcN, dstN, k0, n0, qscale;
    if (bx < 432) {
      src = wa; dst = waT; srcN = C3; dstN = NC; qscale = 1;
      k0 = (bx / 36) * 64; n0 = (bx % 36) * 64;
    } else {
      const int t = bx - 432;
      src = wp; dst = wpT; srcN = NC; dstN = NC; qscale = 0;
      k0 = (t / 12) * 64; n0 = (t % 12) * 64;
    }
    const int tr = threadIdx.x >> 4;        // 0..15
    const int tc = (threadIdx.x & 15) * 4;  // 0,4,..,60
#pragma unroll
    for (int p = 0; p < 4; ++p) {
      const int r = p * 16 + tr;
      const float4 v = *reinterpret_cast<const float4*>(src + (size_t)(k0 + r) * srcN + n0 + tc);
      tile[r][tc + 0] = v.x; tile[r][tc + 1] = v.y;
      tile[r][tc + 2] = v.z; tile[r][tc + 3] = v.w;
    }
    __syncthreads();
#pragma unroll
    for (int p = 0; p < 4; ++p) {
      const int n = p * 16 + tr;   // output row = source column n0+n
      const float sc = (qscale && (n0 + n) < NC) ? KSCALE_LOG2E : 1.0f;
      ushort4 o;
      o.x = f2bf(tile[tc + 0][n] * sc); o.y = f2bf(tile[tc + 1][n] * sc);
      o.z = f2bf(tile[tc + 2][n] * sc); o.w = f2bf(tile[tc + 3][n] * sc);
      *reinterpret_cast<ushort4*>(dst + (size_t)(n0 + n) * dstN + k0 + tc) = o;
    }
  } else {
    const int gid = (bx - 576) * 256 + threadIdx.x;   // < MTOK*NC/4
    const float4 v = reinterpret_cast<const float4*>(x)[gid];
    ushort4 o;
    o.x = f2bf(v.x); o.y = f2bf(v.y); o.z = f2bf(v.z); o.w = f2bf(v.w);
    reinterpret_cast<ushort4*>(xb)[gid] = o;
  }
}

// V slice of qkv [B][T][3C] -> vT [B*NH][HS][T]  (bf16)
__global__ __launch_bounds__(256) void transpose_v(
    const unsigned short* __restrict__ qkv, unsigned short* __restrict__ vT) {
  __shared__ unsigned short tile[64][72];
  const int t0 = blockIdx.x * 64;
  const int bh = blockIdx.y;
  const int b = bh / NHEAD, h = bh - b * NHEAD;
  const unsigned short* src = qkv + (size_t)b * NT * C3 + 2 * NC + h * HS;
  const int r = threadIdx.x >> 3;
  const int c8 = (threadIdx.x & 7) * 8;
  uint4 v0 = *reinterpret_cast<const uint4*>(src + (size_t)(t0 + r) * C3 + c8);
  uint4 v1 = *reinterpret_cast<const uint4*>(src + (size_t)(t0 + r + 32) * C3 + c8);
  *reinterpret_cast<uint4*>(&tile[r][c8]) = v0;
  *reinterpret_cast<uint4*>(&tile[r + 32][c8]) = v1;
  __syncthreads();
  unsigned short* dst = vT + (size_t)bh * HS * NT + t0;
#pragma unroll
  for (int half = 0; half < 2; ++half) {
    const int d = r + half * 32;
    ushort4 o0, o1;
    o0.x = tile[c8 + 0][d]; o0.y = tile[c8 + 1][d];
    o0.z = tile[c8 + 2][d]; o0.w = tile[c8 + 3][d];
    o1.x = tile[c8 + 4][d]; o1.y = tile[c8 + 5][d];
    o1.z = tile[c8 + 6][d]; o1.w = tile[c8 + 7][d];
    *reinterpret_cast<ushort4*>(dst + (size_t)d * NT + c8) = o0;
    *reinterpret_cast<ushort4*>(dst + (size_t)d * NT + c8 + 4) = o1;
  }
}

// ---------------- GEMM 128x128: C[M,N] = A[M,K] @ Bt[N,K]^T ----------------
template <int OUT_BF16>
__global__ __launch_bounds__(256) void gemm128(
    const unsigned short* __restrict__ A,   // [M][K]
    const unsigned short* __restrict__ Bt,  // [N][K]
    void* __restrict__ Cout, int M, int N, int K) {
  __shared__ unsigned short As[128 * 64];
  __shared__ unsigned short Bs[128 * 64];

  const int tid = threadIdx.x;
  const int wave = tid >> 6;
  const int lane = tid & 63;
  const int li = lane & 15;
  const int lq = lane >> 4;
  const int wm = wave & 1;
  const int wn = wave >> 1;
  const int row0 = blockIdx.y * 128;
  const int col0 = blockIdx.x * 128;

  const int crow = lane >> 3;
  const int cchunk = ((lane & 7) ^ crow) * 8;

  f32x4 acc[4][4] = {};

  for (int k0 = 0; k0 < K; k0 += 64) {
#pragma unroll
    for (int i = 0; i < 4; ++i) {
      const int R = wave * 32 + i * 8;
      gload_lds16(A + (size_t)(row0 + R + crow) * K + k0 + cchunk, &As[R * 64]);
      gload_lds16(Bt + (size_t)(col0 + R + crow) * K + k0 + cchunk, &Bs[R * 64]);
    }
    __syncthreads();

#pragma unroll
    for (int ks = 0; ks < 2; ++ks) {
      bf16x8 af[4], bf[4];
#pragma unroll
      for (int f = 0; f < 4; ++f) {
        const int arow = wm * 64 + f * 16 + li;
        af[f] = *reinterpret_cast<const bf16x8*>(&As[arow * 64 + (((ks * 4 + lq) ^ (li & 7)) << 3)]);
        const int brow = wn * 64 + f * 16 + li;
        bf[f] = *reinterpret_cast<const bf16x8*>(&Bs[brow * 64 + (((ks * 4 + lq) ^ (li & 7)) << 3)]);
      }
#pragma unroll
      for (int fa = 0; fa < 4; ++fa)
#pragma unroll
        for (int fb = 0; fb < 4; ++fb)
          acc[fa][fb] = mfma16(af[fa], bf[fb], acc[fa][fb]);
    }
    __syncthreads();
  }

  if (OUT_BF16) {
    unsigned short* Cb = (unsigned short*)Cout;
#pragma unroll
    for (int fa = 0; fa < 4; ++fa) {
      const int gr = row0 + wm * 64 + fa * 16 + lq * 4;
#pragma unroll
      for (int fb = 0; fb < 4; ++fb) {
        const int gc = col0 + wn * 64 + fb * 16 + li;
#pragma unroll
        for (int r = 0; r < 4; ++r)
          Cb[(size_t)(gr + r) * N + gc] = f2bf(acc[fa][fb][r]);
      }
    }
  } else {
    float* Cf = (float*)Cout;
#pragma unroll
    for (int fa = 0; fa < 4; ++fa) {
      const int gr = row0 + wm * 64 + fa * 16 + lq * 4;
#pragma unroll
      for (int fb = 0; fb < 4; ++fb) {
        const int gc = col0 + wn * 64 + fb * 16 + li;
#pragma unroll
        for (int r = 0; r < 4; ++r)
          Cf[(size_t)(gr + r) * N + gc] = acc[fa][fb][r];
      }
    }
  }
}

// ---------------- Flash attention: balanced split-KV chunks (16 tiles) ----------------
// Block = (chunk c, h, b); chunks of <=16 KV tiles. Per (b,h): q-tile i
// (i=0..31) has ceil((i+1)/8) chunks -> 80 chunks -> grid 1920. Halves atomic
// traffic & block-setup count vs 8-tile chunks; balance preserved (chunks are
// 9..16 tiles except the first tier). Unnormalized exp partials merge
// additively via fp32 atomics; l on the MFMA pipe via ones-vector.

#define EXP_STORE(S, SBASE, DOMASK, QROWB)                                     \
  do {                                                                         \
    _Pragma("unroll") for (int n = 0; n < 4; ++n) {                            \
      const int colt = t0 + n * 16 + li;                                       \
      const int c8p = n * 2 + (li >> 3);                                       \
      _Pragma("unroll") for (int r = 0; r < 4; ++r) {                          \
        float v = S[n][r];                                                     \
        if (DOMASK && colt > (QROWB) + r) v = -INFINITY;                       \
        const float p = __builtin_amdgcn_exp2f(v);                             \
        const int prow = (SBASE) + lq * 4 + r;                                 \
        Ps[prow * 64 + ((c8p ^ (prow & 7)) << 3) + (li & 7)] = bft(p);         \
      }                                                                        \
    }                                                                          \
  } while (0)

__global__ __launch_bounds__(256, 4) void attn(
    const unsigned short* __restrict__ qkv,   // [B][T][3C]
    const unsigned short* __restrict__ vT,    // [B*NH][HS][T]
    float* __restrict__ Oacc,                 // [MTOK][NC] fp32, zeroed
    float* __restrict__ lacc) {               // [B*NH][NT]  fp32, zeroed
  __shared__ unsigned short Ks[64 * 64];
  __shared__ unsigned short Vts[64 * 64];
  __shared__ unsigned short Ps[128 * 64];

  const int tid = threadIdx.x;
  const int wave = tid >> 6;
  const int lane = tid & 63;
  const int li = lane & 15;
  const int lq = lane >> 4;

  // ---- chunk decode: c in [0,80) -> (q-tile qi, chunk ck) ----
  // group g=0..3: q-tiles 8g..8g+7, g+1 chunks each; base(g) = 4g(g+1)
  const int c = 79 - (int)blockIdx.x;        // big-qi (16-tile) chunks first
  int g = 0;
#pragma unroll
  for (int gg = 1; gg < 4; ++gg)
    if (4 * gg * (gg + 1) <= c) g = gg;
  const int rem = c - 4 * g * (g + 1);
  const int dq = rem / (g + 1);
  const int qi = 8 * g + dq;                  // q-tile 0..31
  const int ck = rem - dq * (g + 1);          // chunk 0..g
  const int q0 = qi * 128;
  const int ntile = 2 * qi + 2;
  const int tauS = ck * 16;
  const int tauE = (tauS + 16 < ntile) ? tauS + 16 : ntile;

  const int h = blockIdx.y;
  const int b = blockIdx.z;
  const int bh = b * NHEAD + h;

  const size_t baseQ = (size_t)b * NT * C3 + (size_t)h * HS;
  const size_t baseK = baseQ + NC;
  const unsigned short* vbase = vT + (size_t)bh * HS * NT;

  const int sb0 = wave * 16;
  const int sb1 = 64 + wave * 16;

  // Q fragments (A-layout), pre-scaled via waT
  bf16x8 aq0[2], aq1[2];
#pragma unroll
  for (int ks = 0; ks < 2; ++ks) {
    aq0[ks] = *reinterpret_cast<const bf16x8*>(qkv + baseQ + (size_t)(q0 + sb0 + li) * C3 + ks * 32 + lq * 8);
    aq1[ks] = *reinterpret_cast<const bf16x8*>(qkv + baseQ + (size_t)(q0 + sb1 + li) * C3 + ks * 32 + lq * 8);
  }

  // all-ones B fragment for l row-sums on the MFMA pipe
  bf16x8 vones;
#pragma unroll
  for (int i = 0; i < 8; ++i) vones[i] = (__bf16)1.0f;

  f32x4 o0[4] = {}, o1[4] = {};
  f32x4 la0 = {}, la1 = {};

  const int sr = tid >> 3;
  const int sc8 = tid & 7;
  const int slotK0 = sr * 8 + (sc8 ^ (sr & 7));
  const int slotK1 = (sr + 32) * 8 + (sc8 ^ (sr & 7));

  // prefetch first tile of the chunk
  uint4 kr0 = *reinterpret_cast<const uint4*>(qkv + baseK + (size_t)(tauS * 64 + sr) * C3 + sc8 * 8);
  uint4 kr1 = *reinterpret_cast<const uint4*>(qkv + baseK + (size_t)(tauS * 64 + sr + 32) * C3 + sc8 * 8);
  uint4 vr0 = *reinterpret_cast<const uint4*>(vbase + (size_t)sr * NT + tauS * 64 + sc8 * 8);
  uint4 vr1 = *reinterpret_cast<const uint4*>(vbase + (size_t)(sr + 32) * NT + tauS * 64 + sc8 * 8);

  for (int tau = tauS; tau < tauE; ++tau) {
    const int t0 = tau * 64;
    __syncthreads();   // prior tile's LDS reads complete
    reinterpret_cast<uint4*>(Ks)[slotK0] = kr0;
    reinterpret_cast<uint4*>(Ks)[slotK1] = kr1;
    reinterpret_cast<uint4*>(Vts)[slotK0] = vr0;
    reinterpret_cast<uint4*>(Vts)[slotK1] = vr1;
    if (tau + 1 < tauE) {  // prefetch next tile (overlaps compute)
      const int tn = t0 + 64;
      kr0 = *reinterpret_cast<const uint4*>(qkv + baseK + (size_t)(tn + sr) * C3 + sc8 * 8);
      kr1 = *reinterpret_cast<const uint4*>(qkv + baseK + (size_t)(tn + sr + 32) * C3 + sc8 * 8);
      vr0 = *reinterpret_cast<const uint4*>(vbase + (size_t)sr * NT + tn + sc8 * 8);
      vr1 = *reinterpret_cast<const uint4*>(vbase + (size_t)(sr + 32) * NT + tn + sc8 * 8);
    }
    __syncthreads();   // staging visible

    // ---- S = Q K^T ----
    const bool do0 = (t0 != q0 + 64);   // strip0 dead on very last tile
    f32x4 s0[4], s1[4];
    {
      const f32x4 z = {};
#pragma unroll
      for (int n = 0; n < 4; ++n) { s0[n] = z; s1[n] = z; }
#pragma unroll
      for (int ks = 0; ks < 2; ++ks) {
#pragma unroll
        for (int n = 0; n < 4; ++n) {
          const bf16x8 bk = *reinterpret_cast<const bf16x8*>(
              Ks + (n * 16 + li) * 64 + (((ks * 4 + lq) ^ (li & 7)) << 3));
          if (do0) s0[n] = mfma16(aq0[ks], bk, s0[n]);
          s1[n] = mfma16(aq1[ks], bk, s1[n]);
        }
      }
    }

    // ---- exp phase (block-uniform case split) ----
    if (t0 < q0) {
      EXP_STORE(s0, sb0, false, 0);
      EXP_STORE(s1, sb1, false, 0);
    } else if (t0 == q0) {
      EXP_STORE(s0, sb0, true, q0 + sb0 + lq * 4);
      EXP_STORE(s1, sb1, false, 0);
    } else {
      EXP_STORE(s1, sb1, true, q0 + sb1 + lq * 4);
    }

    // Ps rows are wave-private: LDS completion suffices (no barrier)
    asm volatile("s_waitcnt lgkmcnt(0)" ::: "memory");

    // ---- O += P V ; l += P . ones (MFMA pipe) ----
#pragma unroll
    for (int ks = 0; ks < 2; ++ks) {
      const int swz = ((ks * 4 + lq) ^ (li & 7)) << 3;
      const bf16x8 ap0 = *reinterpret_cast<const bf16x8*>(Ps + (sb0 + li) * 64 + swz);
      const bf16x8 ap1 = *reinterpret_cast<const bf16x8*>(Ps + (sb1 + li) * 64 + swz);
      if (do0) la0 = mfma16(ap0, vones, la0);
      la1 = mfma16(ap1, vones, la1);
#pragma unroll
      for (int n = 0; n < 4; ++n) {
        const bf16x8 bv = *reinterpret_cast<const bf16x8*>(Vts + (n * 16 + li) * 64 + swz);
        if (do0) o0[n] = mfma16(ap0, bv, o0[n]);
        o1[n] = mfma16(ap1, bv, o1[n]);
      }
    }
  }

  // ---- atomic partial accumulation (unnormalized; la* uniform across li) ----
  const size_t obase = (size_t)b * NT * NC + (size_t)h * HS;
  float* lrow = lacc + (size_t)bh * NT;
#pragma unroll
  for (int r = 0; r < 4; ++r) {
    const int row = q0 + sb0 + lq * 4 + r;
    if (li == 0) atomicAdd(&lrow[row], la0[r]);
#pragma unroll
    for (int n = 0; n < 4; ++n)
      atomicAdd(&Oacc[obase + (size_t)row * NC + n * 16 + li], o0[n][r]);
  }
#pragma unroll
  for (int r = 0; r < 4; ++r) {
    const int row = q0 + sb1 + lq * 4 + r;
    if (li == 0) atomicAdd(&lrow[row], la1[r]);
#pragma unroll
    for (int n = 0; n < 4; ++n)
      atomicAdd(&Oacc[obase + (size_t)row * NC + n * 16 + li], o1[n][r]);
  }
}

// ---------------- finalize: aob = bf16(Oacc / l) ----------------
__global__ __launch_bounds__(256) void finalize(
    const float* __restrict__ Oacc, const float* __restrict__ lacc,
    unsigned short* __restrict__ aob) {
  const int idx4 = (blockIdx.x * 256 + threadIdx.x);
  if (idx4 >= MTOK * NC / 4) return;
  const int idx = idx4 * 4;
  const int row = idx / NC;
  const int cc = idx - row * NC;
  const int h = cc >> 6;
  const int b = row >> 12;            // NT = 4096
  const int t = row & (NT - 1);
  const float inv = 1.0f / lacc[(size_t)(b * NHEAD + h) * NT + t];
  const float4 v = reinterpret_cast<const float4*>(Oacc)[idx4];
  ushort4 o;
  o.x = bft(v.x * inv); o.y = bft(v.y * inv);
  o.z = bft(v.z * inv); o.w = bft(v.w * inv);
  reinterpret_cast<ushort4*>(aob)[idx4] = o;
}

// ---------------- launch ----------------
extern "C" void kernel_launch(void* const* d_in, const int* in_sizes, int n_in,
                              void* d_out, int out_size, void* d_ws, size_t ws_size,
                              hipStream_t stream) {
  const float* x = (const float*)d_in[0];       // [B,T,C]
  const float* w_attn = (const float*)d_in[1];  // [C, 3C]
  const float* w_proj = (const float*)d_in[2];  // [C, C]
  float* outp = (float*)d_out;

  // ws layout (Oacc aliases xb/waT, which die after gemm1):
  char* w = (char*)d_ws;
  float* Oacc = (float*)w;
  unsigned short* xb = (unsigned short*)w;                       // aliases Oacc (pre-attn)
  unsigned short* waT = xb + (size_t)MTOK * NC;                  // aliases Oacc tail
  float* lacc = Oacc + (size_t)MTOK * NC;
  unsigned short* qkvb = (unsigned short*)(lacc + (size_t)NB * NHEAD * NT);
  unsigned short* aob  = qkvb + (size_t)MTOK * C3;               // [MTOK][NC] bf16
  unsigned short* vTb  = aob + (size_t)MTOK * NC;                // [B*NH][HS][T]
  unsigned short* wpT  = vTb + (size_t)MTOK * NC;                // [NC][NC] bf16

  // prep: 576 transpose tiles + x-cast blocks
  prep<<<576 + MTOK * NC / 4 / 256, 256, 0, stream>>>(x, w_attn, w_proj, xb, waT, wpT);

  // qkv = x @ w_attn (Q rows of waT pre-scaled) -> bf16 [MTOK][3C]
  gemm128<1><<<dim3(C3 / 128, MTOK / 128), 256, 0, stream>>>(xb, waT, qkvb, MTOK, C3, NC);

  // V -> vT [B*NH][HS][T]
  transpose_v<<<dim3(NT / 64, NB * NHEAD), 256, 0, stream>>>(qkvb, vTb);

  // zero partial accumulators (xb/waT now dead)
  hipMemsetAsync(Oacc, 0, ((size_t)MTOK * NC + (size_t)NB * NHEAD * NT) * sizeof(float), stream);

  // attention partials -> Oacc/lacc (1920 balanced 16-tile chunk-blocks)
  attn<<<dim3(80, NHEAD, NB), 256, 0, stream>>>(qkvb, vTb, Oacc, lacc);

  // normalize -> bf16 aob
  finalize<<<(MTOK * NC / 4 + 255) / 256, 256, 0, stream>>>(Oacc, lacc, aob);

  // out = att_out @ w_proj -> fp32 d_out
  gemm128<0><<<dim3(NC / 128, MTOK / 128), 256, 0, stream>>>(aob, wpT, outp, MTOK, NC, NC);
}

// Round 11
// 325.878 us; speedup vs baseline: 1.8925x; 1.8925x over previous
//
#include <hip/hip_runtime.h>
#include <hip/hip_bf16.h>
#include <stdint.h>

// Problem constants
#define NB 2
#define NT 4096
#define NC 768
#define NHEAD 12
#define HS 64
#define MTOK (NB * NT)      // 8192
#define C3 (3 * NC)         // 2304

typedef __bf16 bf16x8 __attribute__((ext_vector_type(8)));
typedef float f32x4 __attribute__((ext_vector_type(4)));

#define KSCALE_LOG2E 0.18033688011f   // (1/sqrt(64)) * log2(e)

__device__ __forceinline__ unsigned short f2bf(float f) {  // RNE
  union { float f; uint32_t u; } v; v.f = f;
  uint32_t r = v.u + 0x7fffu + ((v.u >> 16) & 1u);
  return (unsigned short)(r >> 16);
}
__device__ __forceinline__ unsigned short bft(float f) {   // truncate
  return (unsigned short)(__builtin_bit_cast(unsigned int, f) >> 16);
}

// async global->LDS, 16B per lane: lane i lands at ldsbase + i*16B.
__device__ __forceinline__ void gload_lds16(const unsigned short* g, unsigned short* ldsbase) {
  __builtin_amdgcn_global_load_lds(
      (const __attribute__((address_space(1))) unsigned int*)g,
      (__attribute__((address_space(3))) unsigned int*)ldsbase, 16, 0, 0);
}

__device__ __forceinline__ f32x4 mfma16(bf16x8 a, bf16x8 b, f32x4 c) {
  return __builtin_amdgcn_mfma_f32_16x16x32_bf16(a, b, c, 0, 0, 0);
}

// ---------------- prep: coalesced LDS-tiled transposes + x cast ----------------
__global__ __launch_bounds__(256) void prep(
    const float* __restrict__ x, const float* __restrict__ wa, const float* __restrict__ wp,
    unsigned short* __restrict__ xb, unsigned short* __restrict__ waT,
    unsigned short* __restrict__ wpT) {
  const int bx = blockIdx.x;
  if (bx < 576) {
    __shared__ float tile[64][65];
    const float* src; unsigned short* dst;
    int srcN, dstN, k0, n0, qscale;
    if (bx < 432) {
      src = wa; dst = waT; srcN = C3; dstN = NC; qscale = 1;
      k0 = (bx / 36) * 64; n0 = (bx % 36) * 64;
    } else {
      const int t = bx - 432;
      src = wp; dst = wpT; srcN = NC; dstN = NC; qscale = 0;
      k0 = (t / 12) * 64; n0 = (t % 12) * 64;
    }
    const int tr = threadIdx.x >> 4;        // 0..15
    const int tc = (threadIdx.x & 15) * 4;  // 0,4,..,60
#pragma unroll
    for (int p = 0; p < 4; ++p) {
      const int r = p * 16 + tr;
      const float4 v = *reinterpret_cast<const float4*>(src + (size_t)(k0 + r) * srcN + n0 + tc);
      tile[r][tc + 0] = v.x; tile[r][tc + 1] = v.y;
      tile[r][tc + 2] = v.z; tile[r][tc + 3] = v.w;
    }
    __syncthreads();
#pragma unroll
    for (int p = 0; p < 4; ++p) {
      const int n = p * 16 + tr;   // output row = source column n0+n
      const float sc = (qscale && (n0 + n) < NC) ? KSCALE_LOG2E : 1.0f;
      ushort4 o;
      o.x = f2bf(tile[tc + 0][n] * sc); o.y = f2bf(tile[tc + 1][n] * sc);
      o.z = f2bf(tile[tc + 2][n] * sc); o.w = f2bf(tile[tc + 3][n] * sc);
      *reinterpret_cast<ushort4*>(dst + (size_t)(n0 + n) * dstN + k0 + tc) = o;
    }
  } else {
    const int gid = (bx - 576) * 256 + threadIdx.x;   // < MTOK*NC/4
    const float4 v = reinterpret_cast<const float4*>(x)[gid];
    ushort4 o;
    o.x = f2bf(v.x); o.y = f2bf(v.y); o.z = f2bf(v.z); o.w = f2bf(v.w);
    reinterpret_cast<ushort4*>(xb)[gid] = o;
  }
}

// V slice of qkv [B][T][3C] -> vT [B*NH][HS][T]  (bf16)
__global__ __launch_bounds__(256) void transpose_v(
    const unsigned short* __restrict__ qkv, unsigned short* __restrict__ vT) {
  __shared__ unsigned short tile[64][72];
  const int t0 = blockIdx.x * 64;
  const int bh = blockIdx.y;
  const int b = bh / NHEAD, h = bh - b * NHEAD;
  const unsigned short* src = qkv + (size_t)b * NT * C3 + 2 * NC + h * HS;
  const int r = threadIdx.x >> 3;
  const int c8 = (threadIdx.x & 7) * 8;
  uint4 v0 = *reinterpret_cast<const uint4*>(src + (size_t)(t0 + r) * C3 + c8);
  uint4 v1 = *reinterpret_cast<const uint4*>(src + (size_t)(t0 + r + 32) * C3 + c8);
  *reinterpret_cast<uint4*>(&tile[r][c8]) = v0;
  *reinterpret_cast<uint4*>(&tile[r + 32][c8]) = v1;
  __syncthreads();
  unsigned short* dst = vT + (size_t)bh * HS * NT + t0;
#pragma unroll
  for (int half = 0; half < 2; ++half) {
    const int d = r + half * 32;
    ushort4 o0, o1;
    o0.x = tile[c8 + 0][d]; o0.y = tile[c8 + 1][d];
    o0.z = tile[c8 + 2][d]; o0.w = tile[c8 + 3][d];
    o1.x = tile[c8 + 4][d]; o1.y = tile[c8 + 5][d];
    o1.z = tile[c8 + 6][d]; o1.w = tile[c8 + 7][d];
    *reinterpret_cast<ushort4*>(dst + (size_t)d * NT + c8) = o0;
    *reinterpret_cast<ushort4*>(dst + (size_t)d * NT + c8 + 4) = o1;
  }
}

// ---------------- GEMM 128x128: C[M,N] = A[M,K] @ Bt[N,K]^T ----------------
template <int OUT_BF16>
__global__ __launch_bounds__(256) void gemm128(
    const unsigned short* __restrict__ A,   // [M][K]
    const unsigned short* __restrict__ Bt,  // [N][K]
    void* __restrict__ Cout, int M, int N, int K) {
  __shared__ unsigned short As[128 * 64];
  __shared__ unsigned short Bs[128 * 64];

  const int tid = threadIdx.x;
  const int wave = tid >> 6;
  const int lane = tid & 63;
  const int li = lane & 15;
  const int lq = lane >> 4;
  const int wm = wave & 1;
  const int wn = wave >> 1;
  const int row0 = blockIdx.y * 128;
  const int col0 = blockIdx.x * 128;

  const int crow = lane >> 3;
  const int cchunk = ((lane & 7) ^ crow) * 8;

  f32x4 acc[4][4] = {};

  for (int k0 = 0; k0 < K; k0 += 64) {
#pragma unroll
    for (int i = 0; i < 4; ++i) {
      const int R = wave * 32 + i * 8;
      gload_lds16(A + (size_t)(row0 + R + crow) * K + k0 + cchunk, &As[R * 64]);
      gload_lds16(Bt + (size_t)(col0 + R + crow) * K + k0 + cchunk, &Bs[R * 64]);
    }
    __syncthreads();

#pragma unroll
    for (int ks = 0; ks < 2; ++ks) {
      bf16x8 af[4], bf[4];
#pragma unroll
      for (int f = 0; f < 4; ++f) {
        const int arow = wm * 64 + f * 16 + li;
        af[f] = *reinterpret_cast<const bf16x8*>(&As[arow * 64 + (((ks * 4 + lq) ^ (li & 7)) << 3)]);
        const int brow = wn * 64 + f * 16 + li;
        bf[f] = *reinterpret_cast<const bf16x8*>(&Bs[brow * 64 + (((ks * 4 + lq) ^ (li & 7)) << 3)]);
      }
#pragma unroll
      for (int fa = 0; fa < 4; ++fa)
#pragma unroll
        for (int fb = 0; fb < 4; ++fb)
          acc[fa][fb] = mfma16(af[fa], bf[fb], acc[fa][fb]);
    }
    __syncthreads();
  }

  if (OUT_BF16) {
    unsigned short* Cb = (unsigned short*)Cout;
#pragma unroll
    for (int fa = 0; fa < 4; ++fa) {
      const int gr = row0 + wm * 64 + fa * 16 + lq * 4;
#pragma unroll
      for (int fb = 0; fb < 4; ++fb) {
        const int gc = col0 + wn * 64 + fb * 16 + li;
#pragma unroll
        for (int r = 0; r < 4; ++r)
          Cb[(size_t)(gr + r) * N + gc] = f2bf(acc[fa][fb][r]);
      }
    }
  } else {
    float* Cf = (float*)Cout;
#pragma unroll
    for (int fa = 0; fa < 4; ++fa) {
      const int gr = row0 + wm * 64 + fa * 16 + lq * 4;
#pragma unroll
      for (int fb = 0; fb < 4; ++fb) {
        const int gc = col0 + wn * 64 + fb * 16 + li;
#pragma unroll
        for (int r = 0; r < 4; ++r)
          Cf[(size_t)(gr + r) * N + gc] = acc[fa][fb][r];
      }
    }
  }
}

// ---------------- Flash attention: balanced split-KV chunks (16 tiles) ----------------
// Block = (chunk c, h, b); chunks of <=16 KV tiles. Per (b,h): q-tile i
// (i=0..31) has ceil((i+1)/8) chunks -> 80 chunks -> grid 1920. Unnormalized
// exp partials merge additively via fp32 atomics; l on the MFMA pipe.
// NOTE: plain __launch_bounds__(256) — round 10 showed that adding a
// min-waves bound (256,4) forces VGPR 128->64 and spills accumulators
// (FETCH 104->805 MB). Natural fit is exactly 128 VGPR / 4 blocks per CU.

#define EXP_STORE(S, SBASE, DOMASK, QROWB)                                     \
  do {                                                                         \
    _Pragma("unroll") for (int n = 0; n < 4; ++n) {                            \
      const int colt = t0 + n * 16 + li;                                       \
      const int c8p = n * 2 + (li >> 3);                                       \
      _Pragma("unroll") for (int r = 0; r < 4; ++r) {                          \
        float v = S[n][r];                                                     \
        if (DOMASK && colt > (QROWB) + r) v = -INFINITY;                       \
        const float p = __builtin_amdgcn_exp2f(v);                             \
        const int prow = (SBASE) + lq * 4 + r;                                 \
        Ps[prow * 64 + ((c8p ^ (prow & 7)) << 3) + (li & 7)] = bft(p);         \
      }                                                                        \
    }                                                                          \
  } while (0)

__global__ __launch_bounds__(256) void attn(
    const unsigned short* __restrict__ qkv,   // [B][T][3C]
    const unsigned short* __restrict__ vT,    // [B*NH][HS][T]
    float* __restrict__ Oacc,                 // [MTOK][NC] fp32, zeroed
    float* __restrict__ lacc) {               // [B*NH][NT]  fp32, zeroed
  __shared__ unsigned short Ks[64 * 64];
  __shared__ unsigned short Vts[64 * 64];
  __shared__ unsigned short Ps[128 * 64];

  const int tid = threadIdx.x;
  const int wave = tid >> 6;
  const int lane = tid & 63;
  const int li = lane & 15;
  const int lq = lane >> 4;

  // ---- chunk decode: c in [0,80) -> (q-tile qi, chunk ck) ----
  // group g=0..3: q-tiles 8g..8g+7, g+1 chunks each; base(g) = 4g(g+1)
  const int c = 79 - (int)blockIdx.x;        // big-qi (16-tile) chunks first
  int g = 0;
#pragma unroll
  for (int gg = 1; gg < 4; ++gg)
    if (4 * gg * (gg + 1) <= c) g = gg;
  const int rem = c - 4 * g * (g + 1);
  const int dq = rem / (g + 1);
  const int qi = 8 * g + dq;                  // q-tile 0..31
  const int ck = rem - dq * (g + 1);          // chunk 0..g
  const int q0 = qi * 128;
  const int ntile = 2 * qi + 2;
  const int tauS = ck * 16;
  const int tauE = (tauS + 16 < ntile) ? tauS + 16 : ntile;

  const int h = blockIdx.y;
  const int b = blockIdx.z;
  const int bh = b * NHEAD + h;

  const size_t baseQ = (size_t)b * NT * C3 + (size_t)h * HS;
  const size_t baseK = baseQ + NC;
  const unsigned short* vbase = vT + (size_t)bh * HS * NT;

  const int sb0 = wave * 16;
  const int sb1 = 64 + wave * 16;

  // Q fragments (A-layout), pre-scaled via waT
  bf16x8 aq0[2], aq1[2];
#pragma unroll
  for (int ks = 0; ks < 2; ++ks) {
    aq0[ks] = *reinterpret_cast<const bf16x8*>(qkv + baseQ + (size_t)(q0 + sb0 + li) * C3 + ks * 32 + lq * 8);
    aq1[ks] = *reinterpret_cast<const bf16x8*>(qkv + baseQ + (size_t)(q0 + sb1 + li) * C3 + ks * 32 + lq * 8);
  }

  // all-ones B fragment for l row-sums on the MFMA pipe
  bf16x8 vones;
#pragma unroll
  for (int i = 0; i < 8; ++i) vones[i] = (__bf16)1.0f;

  f32x4 o0[4] = {}, o1[4] = {};
  f32x4 la0 = {}, la1 = {};

  const int sr = tid >> 3;
  const int sc8 = tid & 7;
  const int slotK0 = sr * 8 + (sc8 ^ (sr & 7));
  const int slotK1 = (sr + 32) * 8 + (sc8 ^ (sr & 7));

  // prefetch first tile of the chunk
  uint4 kr0 = *reinterpret_cast<const uint4*>(qkv + baseK + (size_t)(tauS * 64 + sr) * C3 + sc8 * 8);
  uint4 kr1 = *reinterpret_cast<const uint4*>(qkv + baseK + (size_t)(tauS * 64 + sr + 32) * C3 + sc8 * 8);
  uint4 vr0 = *reinterpret_cast<const uint4*>(vbase + (size_t)sr * NT + tauS * 64 + sc8 * 8);
  uint4 vr1 = *reinterpret_cast<const uint4*>(vbase + (size_t)(sr + 32) * NT + tauS * 64 + sc8 * 8);

  for (int tau = tauS; tau < tauE; ++tau) {
    const int t0 = tau * 64;
    __syncthreads();   // prior tile's LDS reads complete
    reinterpret_cast<uint4*>(Ks)[slotK0] = kr0;
    reinterpret_cast<uint4*>(Ks)[slotK1] = kr1;
    reinterpret_cast<uint4*>(Vts)[slotK0] = vr0;
    reinterpret_cast<uint4*>(Vts)[slotK1] = vr1;
    if (tau + 1 < tauE) {  // prefetch next tile (overlaps compute)
      const int tn = t0 + 64;
      kr0 = *reinterpret_cast<const uint4*>(qkv + baseK + (size_t)(tn + sr) * C3 + sc8 * 8);
      kr1 = *reinterpret_cast<const uint4*>(qkv + baseK + (size_t)(tn + sr + 32) * C3 + sc8 * 8);
      vr0 = *reinterpret_cast<const uint4*>(vbase + (size_t)sr * NT + tn + sc8 * 8);
      vr1 = *reinterpret_cast<const uint4*>(vbase + (size_t)(sr + 32) * NT + tn + sc8 * 8);
    }
    __syncthreads();   // staging visible

    // ---- S = Q K^T ----
    const bool do0 = (t0 != q0 + 64);   // strip0 dead on very last tile
    f32x4 s0[4], s1[4];
    {
      const f32x4 z = {};
#pragma unroll
      for (int n = 0; n < 4; ++n) { s0[n] = z; s1[n] = z; }
#pragma unroll
      for (int ks = 0; ks < 2; ++ks) {
#pragma unroll
        for (int n = 0; n < 4; ++n) {
          const bf16x8 bk = *reinterpret_cast<const bf16x8*>(
              Ks + (n * 16 + li) * 64 + (((ks * 4 + lq) ^ (li & 7)) << 3));
          if (do0) s0[n] = mfma16(aq0[ks], bk, s0[n]);
          s1[n] = mfma16(aq1[ks], bk, s1[n]);
        }
      }
    }

    // ---- exp phase (block-uniform case split) ----
    if (t0 < q0) {
      EXP_STORE(s0, sb0, false, 0);
      EXP_STORE(s1, sb1, false, 0);
    } else if (t0 == q0) {
      EXP_STORE(s0, sb0, true, q0 + sb0 + lq * 4);
      EXP_STORE(s1, sb1, false, 0);
    } else {
      EXP_STORE(s1, sb1, true, q0 + sb1 + lq * 4);
    }

    // Ps rows are wave-private: LDS completion suffices (no barrier)
    asm volatile("s_waitcnt lgkmcnt(0)" ::: "memory");

    // ---- O += P V ; l += P . ones (MFMA pipe) ----
#pragma unroll
    for (int ks = 0; ks < 2; ++ks) {
      const int swz = ((ks * 4 + lq) ^ (li & 7)) << 3;
      const bf16x8 ap0 = *reinterpret_cast<const bf16x8*>(Ps + (sb0 + li) * 64 + swz);
      const bf16x8 ap1 = *reinterpret_cast<const bf16x8*>(Ps + (sb1 + li) * 64 + swz);
      if (do0) la0 = mfma16(ap0, vones, la0);
      la1 = mfma16(ap1, vones, la1);
#pragma unroll
      for (int n = 0; n < 4; ++n) {
        const bf16x8 bv = *reinterpret_cast<const bf16x8*>(Vts + (n * 16 + li) * 64 + swz);
        if (do0) o0[n] = mfma16(ap0, bv, o0[n]);
        o1[n] = mfma16(ap1, bv, o1[n]);
      }
    }
  }

  // ---- atomic partial accumulation (unnormalized; la* uniform across li) ----
  const size_t obase = (size_t)b * NT * NC + (size_t)h * HS;
  float* lrow = lacc + (size_t)bh * NT;
#pragma unroll
  for (int r = 0; r < 4; ++r) {
    const int row = q0 + sb0 + lq * 4 + r;
    if (li == 0) atomicAdd(&lrow[row], la0[r]);
#pragma unroll
    for (int n = 0; n < 4; ++n)
      atomicAdd(&Oacc[obase + (size_t)row * NC + n * 16 + li], o0[n][r]);
  }
#pragma unroll
  for (int r = 0; r < 4; ++r) {
    const int row = q0 + sb1 + lq * 4 + r;
    if (li == 0) atomicAdd(&lrow[row], la1[r]);
#pragma unroll
    for (int n = 0; n < 4; ++n)
      atomicAdd(&Oacc[obase + (size_t)row * NC + n * 16 + li], o1[n][r]);
  }
}

// ---------------- finalize: aob = bf16(Oacc / l) ----------------
__global__ __launch_bounds__(256) void finalize(
    const float* __restrict__ Oacc, const float* __restrict__ lacc,
    unsigned short* __restrict__ aob) {
  const int idx4 = (blockIdx.x * 256 + threadIdx.x);
  if (idx4 >= MTOK * NC / 4) return;
  const int idx = idx4 * 4;
  const int row = idx / NC;
  const int cc = idx - row * NC;
  const int h = cc >> 6;
  const int b = row >> 12;            // NT = 4096
  const int t = row & (NT - 1);
  const float inv = 1.0f / lacc[(size_t)(b * NHEAD + h) * NT + t];
  const float4 v = reinterpret_cast<const float4*>(Oacc)[idx4];
  ushort4 o;
  o.x = bft(v.x * inv); o.y = bft(v.y * inv);
  o.z = bft(v.z * inv); o.w = bft(v.w * inv);
  reinterpret_cast<ushort4*>(aob)[idx4] = o;
}

// ---------------- launch ----------------
extern "C" void kernel_launch(void* const* d_in, const int* in_sizes, int n_in,
                              void* d_out, int out_size, void* d_ws, size_t ws_size,
                              hipStream_t stream) {
  const float* x = (const float*)d_in[0];       // [B,T,C]
  const float* w_attn = (const float*)d_in[1];  // [C, 3C]
  const float* w_proj = (const float*)d_in[2];  // [C, C]
  float* outp = (float*)d_out;

  // ws layout (Oacc aliases xb/waT, which die after gemm1):
  char* w = (char*)d_ws;
  float* Oacc = (float*)w;
  unsigned short* xb = (unsigned short*)w;                       // aliases Oacc (pre-attn)
  unsigned short* waT = xb + (size_t)MTOK * NC;                  // aliases Oacc tail
  float* lacc = Oacc + (size_t)MTOK * NC;
  unsigned short* qkvb = (unsigned short*)(lacc + (size_t)NB * NHEAD * NT);
  unsigned short* aob  = qkvb + (size_t)MTOK * C3;               // [MTOK][NC] bf16
  unsigned short* vTb  = aob + (size_t)MTOK * NC;                // [B*NH][HS][T]
  unsigned short* wpT  = vTb + (size_t)MTOK * NC;                // [NC][NC] bf16

  // prep: 576 transpose tiles + x-cast blocks
  prep<<<576 + MTOK * NC / 4 / 256, 256, 0, stream>>>(x, w_attn, w_proj, xb, waT, wpT);

  // qkv = x @ w_attn (Q rows of waT pre-scaled) -> bf16 [MTOK][3C]
  gemm128<1><<<dim3(C3 / 128, MTOK / 128), 256, 0, stream>>>(xb, waT, qkvb, MTOK, C3, NC);

  // V -> vT [B*NH][HS][T]
  transpose_v<<<dim3(NT / 64, NB * NHEAD), 256, 0, stream>>>(qkvb, vTb);

  // zero partial accumulators (xb/waT now dead)
  hipMemsetAsync(Oacc, 0, ((size_t)MTOK * NC + (size_t)NB * NHEAD * NT) * sizeof(float), stream);

  // attention partials -> Oacc/lacc (1920 balanced 16-tile chunk-blocks)
  attn<<<dim3(80, NHEAD, NB), 256, 0, stream>>>(qkvb, vTb, Oacc, lacc);

  // normalize -> bf16 aob
  finalize<<<(MTOK * NC / 4 + 255) / 256, 256, 0, stream>>>(Oacc, lacc, aob);

  // out = att_out @ w_proj -> fp32 d_out
  gemm128<0><<<dim3(NC / 128, MTOK / 128), 256, 0, stream>>>(aob, wpT, outp, MTOK, NC, NC);
}

// Round 12
// 310.325 us; speedup vs baseline: 1.9874x; 1.0501x over previous
//
#include <hip/hip_runtime.h>
#include <hip/hip_bf16.h>
#include <stdint.h>

// Problem constants
#define NB 2
#define NT 4096
#define NC 768
#define NHEAD 12
#define HS 64
#define MTOK (NB * NT)      // 8192
#define C3 (3 * NC)         // 2304

typedef __bf16 bf16x8 __attribute__((ext_vector_type(8)));
typedef float f32x4 __attribute__((ext_vector_type(4)));

#define KSCALE_LOG2E 0.18033688011f   // (1/sqrt(64)) * log2(e)

__device__ __forceinline__ unsigned short f2bf(float f) {  // RNE
  union { float f; uint32_t u; } v; v.f = f;
  uint32_t r = v.u + 0x7fffu + ((v.u >> 16) & 1u);
  return (unsigned short)(r >> 16);
}
__device__ __forceinline__ unsigned short bft(float f) {   // truncate
  return (unsigned short)(__builtin_bit_cast(unsigned int, f) >> 16);
}

// async global->LDS, 16B per lane: lane i lands at ldsbase + i*16B.
__device__ __forceinline__ void gload_lds16(const unsigned short* g, unsigned short* ldsbase) {
  __builtin_amdgcn_global_load_lds(
      (const __attribute__((address_space(1))) unsigned int*)g,
      (__attribute__((address_space(3))) unsigned int*)ldsbase, 16, 0, 0);
}

__device__ __forceinline__ f32x4 mfma16(bf16x8 a, bf16x8 b, f32x4 c) {
  return __builtin_amdgcn_mfma_f32_16x16x32_bf16(a, b, c, 0, 0, 0);
}

// ---------------- prep: coalesced LDS-tiled transposes + x cast ----------------
__global__ __launch_bounds__(256) void prep(
    const float* __restrict__ x, const float* __restrict__ wa, const float* __restrict__ wp,
    unsigned short* __restrict__ xb, unsigned short* __restrict__ waT,
    unsigned short* __restrict__ wpT) {
  const int bx = blockIdx.x;
  if (bx < 576) {
    __shared__ float tile[64][65];
    const float* src; unsigned short* dst;
    int srcN, dstN, k0, n0, qscale;
    if (bx < 432) {
      src = wa; dst = waT; srcN = C3; dstN = NC; qscale = 1;
      k0 = (bx / 36) * 64; n0 = (bx % 36) * 64;
    } else {
      const int t = bx - 432;
      src = wp; dst = wpT; srcN = NC; dstN = NC; qscale = 0;
      k0 = (t / 12) * 64; n0 = (t % 12) * 64;
    }
    const int tr = threadIdx.x >> 4;        // 0..15
    const int tc = (threadIdx.x & 15) * 4;  // 0,4,..,60
#pragma unroll
    for (int p = 0; p < 4; ++p) {
      const int r = p * 16 + tr;
      const float4 v = *reinterpret_cast<const float4*>(src + (size_t)(k0 + r) * srcN + n0 + tc);
      tile[r][tc + 0] = v.x; tile[r][tc + 1] = v.y;
      tile[r][tc + 2] = v.z; tile[r][tc + 3] = v.w;
    }
    __syncthreads();
#pragma unroll
    for (int p = 0; p < 4; ++p) {
      const int n = p * 16 + tr;   // output row = source column n0+n
      const float sc = (qscale && (n0 + n) < NC) ? KSCALE_LOG2E : 1.0f;
      ushort4 o;
      o.x = f2bf(tile[tc + 0][n] * sc); o.y = f2bf(tile[tc + 1][n] * sc);
      o.z = f2bf(tile[tc + 2][n] * sc); o.w = f2bf(tile[tc + 3][n] * sc);
      *reinterpret_cast<ushort4*>(dst + (size_t)(n0 + n) * dstN + k0 + tc) = o;
    }
  } else {
    const int gid = (bx - 576) * 256 + threadIdx.x;   // < MTOK*NC/4
    const float4 v = reinterpret_cast<const float4*>(x)[gid];
    ushort4 o;
    o.x = f2bf(v.x); o.y = f2bf(v.y); o.z = f2bf(v.z); o.w = f2bf(v.w);
    reinterpret_cast<ushort4*>(xb)[gid] = o;
  }
}

// ---------------- GEMM 128x128: C[M,N] = A[M,K] @ Bt[N,K]^T ----------------
// OUT_BF16=1 (gemm1): blocks with col0 >= 2*NC hold the V tile -> transpose
// in-block via smem (16B-chunk XOR swizzle) and write straight to vT
// [B*NH][HS][T]; qkvb's V slice is never written. Other blocks write qkvb rows.
template <int OUT_BF16>
__global__ __launch_bounds__(256) void gemm128(
    const unsigned short* __restrict__ A,   // [M][K]
    const unsigned short* __restrict__ Bt,  // [N][K]
    void* __restrict__ Cout,
    unsigned short* __restrict__ vT,        // used only by OUT_BF16 V-blocks
    int M, int N, int K) {
  __shared__ unsigned short smem[2 * 128 * 64];
  unsigned short* As = smem;
  unsigned short* Bs = smem + 128 * 64;

  const int tid = threadIdx.x;
  const int wave = tid >> 6;
  const int lane = tid & 63;
  const int li = lane & 15;
  const int lq = lane >> 4;
  const int wm = wave & 1;
  const int wn = wave >> 1;
  const int row0 = blockIdx.y * 128;
  const int col0 = blockIdx.x * 128;

  const int crow = lane >> 3;
  const int cchunk = ((lane & 7) ^ crow) * 8;

  f32x4 acc[4][4] = {};

  for (int k0 = 0; k0 < K; k0 += 64) {
#pragma unroll
    for (int i = 0; i < 4; ++i) {
      const int R = wave * 32 + i * 8;
      gload_lds16(A + (size_t)(row0 + R + crow) * K + k0 + cchunk, &As[R * 64]);
      gload_lds16(Bt + (size_t)(col0 + R + crow) * K + k0 + cchunk, &Bs[R * 64]);
    }
    __syncthreads();

#pragma unroll
    for (int ks = 0; ks < 2; ++ks) {
      bf16x8 af[4], bf[4];
#pragma unroll
      for (int f = 0; f < 4; ++f) {
        const int arow = wm * 64 + f * 16 + li;
        af[f] = *reinterpret_cast<const bf16x8*>(&As[arow * 64 + (((ks * 4 + lq) ^ (li & 7)) << 3)]);
        const int brow = wn * 64 + f * 16 + li;
        bf[f] = *reinterpret_cast<const bf16x8*>(&Bs[brow * 64 + (((ks * 4 + lq) ^ (li & 7)) << 3)]);
      }
#pragma unroll
      for (int fa = 0; fa < 4; ++fa)
#pragma unroll
        for (int fb = 0; fb < 4; ++fb)
          acc[fa][fb] = mfma16(af[fa], bf[fb], acc[fa][fb]);
    }
    __syncthreads();   // also protects smem reuse in the fused epilogue
  }

  if (OUT_BF16) {
    if (col0 >= 2 * NC) {
      // ---- fused V transpose: acc -> smem[c][t] -> vT[bh][d][t] ----
      const int b = row0 >> 12;            // row0 / NT
      const int t0r = row0 & (NT - 1);
      const int h0 = (col0 - 2 * NC) >> 6;
      // write phase: value at (c = head-col, t = token) with 16B-chunk XOR swizzle
#pragma unroll
      for (int fa = 0; fa < 4; ++fa) {
#pragma unroll
        for (int fb = 0; fb < 4; ++fb) {
          const int cc = wn * 64 + fb * 16 + li;
#pragma unroll
          for (int r = 0; r < 4; ++r) {
            const int tt = wm * 64 + fa * 16 + lq * 4 + r;
            const int slot = cc * 16 + ((tt >> 3) ^ (cc & 15));
            smem[slot * 8 + (tt & 7)] = f2bf(acc[fa][fb][r]);
          }
        }
      }
      __syncthreads();
      // read phase: 16 lanes cover one c-row's 16 chunks -> 256B coalesced stores
      const int ch = tid & 15;
#pragma unroll
      for (int j = 0; j < 8; ++j) {
        const int cc = (tid >> 4) + 16 * j;
        const uint4 v = *reinterpret_cast<const uint4*>(
            smem + (size_t)(cc * 16 + (ch ^ (cc & 15))) * 8);
        const int bh = b * NHEAD + h0 + (cc >> 6);
        const int d = cc & 63;
        *reinterpret_cast<uint4*>(vT + (size_t)bh * HS * NT + (size_t)d * NT + t0r + ch * 8) = v;
      }
    } else {
      unsigned short* Cb = (unsigned short*)Cout;
#pragma unroll
      for (int fa = 0; fa < 4; ++fa) {
        const int gr = row0 + wm * 64 + fa * 16 + lq * 4;
#pragma unroll
        for (int fb = 0; fb < 4; ++fb) {
          const int gc = col0 + wn * 64 + fb * 16 + li;
#pragma unroll
          for (int r = 0; r < 4; ++r)
            Cb[(size_t)(gr + r) * N + gc] = f2bf(acc[fa][fb][r]);
        }
      }
    }
  } else {
    float* Cf = (float*)Cout;
#pragma unroll
    for (int fa = 0; fa < 4; ++fa) {
      const int gr = row0 + wm * 64 + fa * 16 + lq * 4;
#pragma unroll
      for (int fb = 0; fb < 4; ++fb) {
        const int gc = col0 + wn * 64 + fb * 16 + li;
#pragma unroll
        for (int r = 0; r < 4; ++r)
          Cf[(size_t)(gr + r) * N + gc] = acc[fa][fb][r];
      }
    }
  }
}

// ---------------- Flash attention: balanced split-KV chunks (8 tiles) ----------------
// Round-9 best-measured config: chunks of <=8 KV tiles, 144 per (b,h), grid
// 3456. Round-11 A/B showed halving atomics (chunk16) does NOT help — block
// parallelism matters more. Unnormalized exp (Q pre-scaled in waT, log2
// domain): partials merge additively via fp32 atomics; l on the MFMA pipe.
// NOTE: plain __launch_bounds__(256) — (256,4) forces VGPR 128->64 + spill.

#define EXP_STORE(S, SBASE, DOMASK, QROWB)                                     \
  do {                                                                         \
    _Pragma("unroll") for (int n = 0; n < 4; ++n) {                            \
      const int colt = t0 + n * 16 + li;                                       \
      const int c8p = n * 2 + (li >> 3);                                       \
      _Pragma("unroll") for (int r = 0; r < 4; ++r) {                          \
        float v = S[n][r];                                                     \
        if (DOMASK && colt > (QROWB) + r) v = -INFINITY;                       \
        const float p = __builtin_amdgcn_exp2f(v);                             \
        const int prow = (SBASE) + lq * 4 + r;                                 \
        Ps[prow * 64 + ((c8p ^ (prow & 7)) << 3) + (li & 7)] = bft(p);         \
      }                                                                        \
    }                                                                          \
  } while (0)

__global__ __launch_bounds__(256) void attn(
    const unsigned short* __restrict__ qkv,   // [B][T][3C] (V slice unused)
    const unsigned short* __restrict__ vT,    // [B*NH][HS][T]
    float* __restrict__ Oacc,                 // [MTOK][NC] fp32, zeroed
    float* __restrict__ lacc) {               // [B*NH][NT]  fp32, zeroed
  __shared__ unsigned short Ks[64 * 64];
  __shared__ unsigned short Vts[64 * 64];
  __shared__ unsigned short Ps[128 * 64];

  const int tid = threadIdx.x;
  const int wave = tid >> 6;
  const int lane = tid & 63;
  const int li = lane & 15;
  const int lq = lane >> 4;

  // ---- chunk decode: c in [0,144) -> (q-tile qi, chunk ck) ----
  const int c = 143 - (int)blockIdx.x;
  int g = 0;
#pragma unroll
  for (int gg = 1; gg < 8; ++gg)
    if (2 * gg * (gg + 1) <= c) g = gg;       // group g: q-tiles 4g..4g+3, g+1 chunks each
  const int rem = c - 2 * g * (g + 1);
  const int dq = rem / (g + 1);
  const int qi = 4 * g + dq;                  // q-tile 0..31
  const int ck = rem - dq * (g + 1);          // chunk 0..g
  const int q0 = qi * 128;
  const int ntile = 2 * qi + 2;
  const int tauS = ck * 8;
  const int tauE = (tauS + 8 < ntile) ? tauS + 8 : ntile;

  const int h = blockIdx.y;
  const int b = blockIdx.z;
  const int bh = b * NHEAD + h;

  const size_t baseQ = (size_t)b * NT * C3 + (size_t)h * HS;
  const size_t baseK = baseQ + NC;
  const unsigned short* vbase = vT + (size_t)bh * HS * NT;

  const int sb0 = wave * 16;
  const int sb1 = 64 + wave * 16;

  // Q fragments (A-layout), pre-scaled via waT
  bf16x8 aq0[2], aq1[2];
#pragma unroll
  for (int ks = 0; ks < 2; ++ks) {
    aq0[ks] = *reinterpret_cast<const bf16x8*>(qkv + baseQ + (size_t)(q0 + sb0 + li) * C3 + ks * 32 + lq * 8);
    aq1[ks] = *reinterpret_cast<const bf16x8*>(qkv + baseQ + (size_t)(q0 + sb1 + li) * C3 + ks * 32 + lq * 8);
  }

  // all-ones B fragment for l row-sums on the MFMA pipe
  bf16x8 vones;
#pragma unroll
  for (int i = 0; i < 8; ++i) vones[i] = (__bf16)1.0f;

  f32x4 o0[4] = {}, o1[4] = {};
  f32x4 la0 = {}, la1 = {};

  const int sr = tid >> 3;
  const int sc8 = tid & 7;
  const int slotK0 = sr * 8 + (sc8 ^ (sr & 7));
  const int slotK1 = (sr + 32) * 8 + (sc8 ^ (sr & 7));

  // prefetch first tile of the chunk
  uint4 kr0 = *reinterpret_cast<const uint4*>(qkv + baseK + (size_t)(tauS * 64 + sr) * C3 + sc8 * 8);
  uint4 kr1 = *reinterpret_cast<const uint4*>(qkv + baseK + (size_t)(tauS * 64 + sr + 32) * C3 + sc8 * 8);
  uint4 vr0 = *reinterpret_cast<const uint4*>(vbase + (size_t)sr * NT + tauS * 64 + sc8 * 8);
  uint4 vr1 = *reinterpret_cast<const uint4*>(vbase + (size_t)(sr + 32) * NT + tauS * 64 + sc8 * 8);

  for (int tau = tauS; tau < tauE; ++tau) {
    const int t0 = tau * 64;
    __syncthreads();   // prior tile's LDS reads complete
    reinterpret_cast<uint4*>(Ks)[slotK0] = kr0;
    reinterpret_cast<uint4*>(Ks)[slotK1] = kr1;
    reinterpret_cast<uint4*>(Vts)[slotK0] = vr0;
    reinterpret_cast<uint4*>(Vts)[slotK1] = vr1;
    if (tau + 1 < tauE) {  // prefetch next tile (overlaps compute)
      const int tn = t0 + 64;
      kr0 = *reinterpret_cast<const uint4*>(qkv + baseK + (size_t)(tn + sr) * C3 + sc8 * 8);
      kr1 = *reinterpret_cast<const uint4*>(qkv + baseK + (size_t)(tn + sr + 32) * C3 + sc8 * 8);
      vr0 = *reinterpret_cast<const uint4*>(vbase + (size_t)sr * NT + tn + sc8 * 8);
      vr1 = *reinterpret_cast<const uint4*>(vbase + (size_t)(sr + 32) * NT + tn + sc8 * 8);
    }
    __syncthreads();   // staging visible

    // ---- S = Q K^T ----
    const bool do0 = (t0 != q0 + 64);   // strip0 dead on very last tile
    f32x4 s0[4], s1[4];
    {
      const f32x4 z = {};
#pragma unroll
      for (int n = 0; n < 4; ++n) { s0[n] = z; s1[n] = z; }
#pragma unroll
      for (int ks = 0; ks < 2; ++ks) {
#pragma unroll
        for (int n = 0; n < 4; ++n) {
          const bf16x8 bk = *reinterpret_cast<const bf16x8*>(
              Ks + (n * 16 + li) * 64 + (((ks * 4 + lq) ^ (li & 7)) << 3));
          if (do0) s0[n] = mfma16(aq0[ks], bk, s0[n]);
          s1[n] = mfma16(aq1[ks], bk, s1[n]);
        }
      }
    }

    // ---- exp phase (block-uniform case split) ----
    if (t0 < q0) {
      EXP_STORE(s0, sb0, false, 0);
      EXP_STORE(s1, sb1, false, 0);
    } else if (t0 == q0) {
      EXP_STORE(s0, sb0, true, q0 + sb0 + lq * 4);
      EXP_STORE(s1, sb1, false, 0);
    } else {
      EXP_STORE(s1, sb1, true, q0 + sb1 + lq * 4);
    }

    // Ps rows are wave-private: LDS completion suffices (no barrier)
    asm volatile("s_waitcnt lgkmcnt(0)" ::: "memory");

    // ---- O += P V ; l += P . ones (MFMA pipe) ----
#pragma unroll
    for (int ks = 0; ks < 2; ++ks) {
      const int swz = ((ks * 4 + lq) ^ (li & 7)) << 3;
      const bf16x8 ap0 = *reinterpret_cast<const bf16x8*>(Ps + (sb0 + li) * 64 + swz);
      const bf16x8 ap1 = *reinterpret_cast<const bf16x8*>(Ps + (sb1 + li) * 64 + swz);
      if (do0) la0 = mfma16(ap0, vones, la0);
      la1 = mfma16(ap1, vones, la1);
#pragma unroll
      for (int n = 0; n < 4; ++n) {
        const bf16x8 bv = *reinterpret_cast<const bf16x8*>(Vts + (n * 16 + li) * 64 + swz);
        if (do0) o0[n] = mfma16(ap0, bv, o0[n]);
        o1[n] = mfma16(ap1, bv, o1[n]);
      }
    }
  }

  // ---- atomic partial accumulation (unnormalized; la* uniform across li) ----
  const size_t obase = (size_t)b * NT * NC + (size_t)h * HS;
  float* lrow = lacc + (size_t)bh * NT;
#pragma unroll
  for (int r = 0; r < 4; ++r) {
    const int row = q0 + sb0 + lq * 4 + r;
    if (li == 0) atomicAdd(&lrow[row], la0[r]);
#pragma unroll
    for (int n = 0; n < 4; ++n)
      atomicAdd(&Oacc[obase + (size_t)row * NC + n * 16 + li], o0[n][r]);
  }
#pragma unroll
  for (int r = 0; r < 4; ++r) {
    const int row = q0 + sb1 + lq * 4 + r;
    if (li == 0) atomicAdd(&lrow[row], la1[r]);
#pragma unroll
    for (int n = 0; n < 4; ++n)
      atomicAdd(&Oacc[obase + (size_t)row * NC + n * 16 + li], o1[n][r]);
  }
}

// ---------------- finalize: aob = bf16(Oacc / l) ----------------
__global__ __launch_bounds__(256) void finalize(
    const float* __restrict__ Oacc, const float* __restrict__ lacc,
    unsigned short* __restrict__ aob) {
  const int idx4 = (blockIdx.x * 256 + threadIdx.x);
  if (idx4 >= MTOK * NC / 4) return;
  const int idx = idx4 * 4;
  const int row = idx / NC;
  const int cc = idx - row * NC;
  const int h = cc >> 6;
  const int b = row >> 12;            // NT = 4096
  const int t = row & (NT - 1);
  const float inv = 1.0f / lacc[(size_t)(b * NHEAD + h) * NT + t];
  const float4 v = reinterpret_cast<const float4*>(Oacc)[idx4];
  ushort4 o;
  o.x = bft(v.x * inv); o.y = bft(v.y * inv);
  o.z = bft(v.z * inv); o.w = bft(v.w * inv);
  reinterpret_cast<ushort4*>(aob)[idx4] = o;
}

// ---------------- launch ----------------
extern "C" void kernel_launch(void* const* d_in, const int* in_sizes, int n_in,
                              void* d_out, int out_size, void* d_ws, size_t ws_size,
                              hipStream_t stream) {
  const float* x = (const float*)d_in[0];       // [B,T,C]
  const float* w_attn = (const float*)d_in[1];  // [C, 3C]
  const float* w_proj = (const float*)d_in[2];  // [C, C]
  float* outp = (float*)d_out;

  // ws layout (Oacc aliases xb/waT, which die after gemm1):
  char* w = (char*)d_ws;
  float* Oacc = (float*)w;
  unsigned short* xb = (unsigned short*)w;                       // aliases Oacc (pre-attn)
  unsigned short* waT = xb + (size_t)MTOK * NC;                  // aliases Oacc tail
  float* lacc = Oacc + (size_t)MTOK * NC;
  unsigned short* qkvb = (unsigned short*)(lacc + (size_t)NB * NHEAD * NT);
  unsigned short* aob  = qkvb + (size_t)MTOK * C3;               // [MTOK][NC] bf16
  unsigned short* vTb  = aob + (size_t)MTOK * NC;                // [B*NH][HS][T]
  unsigned short* wpT  = vTb + (size_t)MTOK * NC;                // [NC][NC] bf16

  // prep: 576 transpose tiles + x-cast blocks
  prep<<<576 + MTOK * NC / 4 / 256, 256, 0, stream>>>(x, w_attn, w_proj, xb, waT, wpT);

  // qkv = x @ w_attn (Q rows of waT pre-scaled); V blocks write vTb directly
  gemm128<1><<<dim3(C3 / 128, MTOK / 128), 256, 0, stream>>>(xb, waT, qkvb, vTb, MTOK, C3, NC);

  // zero partial accumulators (xb/waT now dead)
  hipMemsetAsync(Oacc, 0, ((size_t)MTOK * NC + (size_t)NB * NHEAD * NT) * sizeof(float), stream);

  // attention partials -> Oacc/lacc (3456 balanced 8-tile chunk-blocks)
  attn<<<dim3(144, NHEAD, NB), 256, 0, stream>>>(qkvb, vTb, Oacc, lacc);

  // normalize -> bf16 aob
  finalize<<<(MTOK * NC / 4 + 255) / 256, 256, 0, stream>>>(Oacc, lacc, aob);

  // out = att_out @ w_proj -> fp32 d_out
  gemm128<0><<<dim3(NC / 128, MTOK / 128), 256, 0, stream>>>(aob, wpT, outp, nullptr, MTOK, NC, NC);
}